// Round 7
// baseline (1226.253 us; speedup 1.0000x reference)
//
#include <hip/hip_runtime.h>
#include <hip/hip_bf16.h>
#include <math.h>

#define DEVFN __device__ __forceinline__

typedef __attribute__((ext_vector_type(8))) short bf16x8;
typedef __attribute__((ext_vector_type(8))) unsigned short u16x8;
typedef __attribute__((ext_vector_type(4))) float f32x4;

static constexpr int Bn = 4, Sn = 256, En = 1024, Hn = 16;
static constexpr int Mn = 65536, Kt = 32, FFn = 4096;
static constexpr int NT = Bn * Sn;           // 1024 tokens

DEVFN unsigned short f2b(float f) {          // f32 -> bf16 RNE
  unsigned int u = __float_as_uint(f);
  unsigned int r = (u + 0x7FFFu + ((u >> 16) & 1u)) >> 16;
  return (unsigned short)r;
}

DEVFN unsigned okey16(unsigned short u) {    // order-preserving bf16 -> u16
  return (unsigned)(u ^ ((u >> 15) ? 0xFFFFu : 0x8000u)) & 0xFFFFu;
}

typedef const __attribute__((address_space(1))) void* as1cv_t;
typedef __attribute__((address_space(3))) void* as3v_t;
DEVFN void gload16(const void* g, void* l) {   // async global->LDS, 16B/lane
  __builtin_amdgcn_global_load_lds((as1cv_t)g, (as3v_t)l, 16, 0, 0);
}
#define MEMFENCE asm volatile("" ::: "memory")

// ---------------- transpose W[R][C] f32 -> out[C][R] bf16 ----------------
__global__ __launch_bounds__(256) void k_transpose_bf16(
    const float* __restrict__ in, unsigned short* __restrict__ out, int R, int C) {
  __shared__ float tile[64][65];
  int tx = threadIdx.x & 63, ty = threadIdx.x >> 6;
  int c0 = blockIdx.x * 64, r0 = blockIdx.y * 64;
  #pragma unroll
  for (int i = 0; i < 16; i++) {
    int r = ty + i * 4;
    tile[tx][r] = in[(size_t)(r0 + r) * C + (c0 + tx)];
  }
  __syncthreads();
  #pragma unroll
  for (int i = 0; i < 16; i++) {
    int c = ty + i * 4;
    out[(size_t)(c0 + c) * R + (r0 + tx)] = f2b(tile[c][tx]);
  }
}

// ---------------- f32 -> bf16 elementwise (x4) ----------------
__global__ __launch_bounds__(256) void k_cvt_bf16(
    const float* __restrict__ in, unsigned short* __restrict__ out, int n4) {
  int i = blockIdx.x * 256 + threadIdx.x;
  if (i >= n4) return;
  float4 v = ((const float4*)in)[i];
  uint2 o;
  o.x = (unsigned int)f2b(v.x) | ((unsigned int)f2b(v.y) << 16);
  o.y = (unsigned int)f2b(v.z) | ((unsigned int)f2b(v.w) << 16);
  ((uint2*)out)[i] = o;
}

// ---------------- concat up to 3 x 1024-f32 vectors ----------------
__global__ __launch_bounds__(256) void k_concat3(
    const float* __restrict__ a, const float* __restrict__ b,
    const float* __restrict__ c, float* __restrict__ o) {
  int i = blockIdx.x * 256 + threadIdx.x;
  float v = (i < 1024) ? a[i] : (i < 2048) ? b[i - 1024] : c[i - 2048];
  o[i] = v;
}

// ---- mem_keys row-normalize + cvt to bf16 (folds cosine norm into B) ----
__global__ __launch_bounds__(256) void k_normcvt(
    const float* __restrict__ mk, unsigned short* __restrict__ out) {
  int m = blockIdx.x, t = threadIdx.x;
  float4 v = ((const float4*)(mk + (size_t)m * En))[t];
  float ss = v.x*v.x + v.y*v.y + v.z*v.z + v.w*v.w;
  #pragma unroll
  for (int d = 32; d; d >>= 1) ss += __shfl_down(ss, d);
  __shared__ float red[4];
  int lane = t & 63, w = t >> 6;
  if (lane == 0) red[w] = ss;
  __syncthreads();
  float rs = 1.0f / fmaxf(sqrtf(red[0] + red[1] + red[2] + red[3]), 1e-12f);
  uint2 o;
  o.x = (unsigned int)f2b(v.x * rs) | ((unsigned int)f2b(v.y * rs) << 16);
  o.y = (unsigned int)f2b(v.z * rs) | ((unsigned int)f2b(v.w * rs) << 16);
  ((uint2*)(out + (size_t)m * En))[t] = o;
}

// ---------------- LayerNorm over rows of [NT][En] ----------------
__global__ __launch_bounds__(256) void k_layernorm(
    const float* __restrict__ in, const float* __restrict__ g, const float* __restrict__ bb,
    float* __restrict__ outf, unsigned short* __restrict__ outb) {
  int n = blockIdx.x, t = threadIdx.x;
  float4 v = ((const float4*)(in + (size_t)n * En))[t];
  float s  = v.x + v.y + v.z + v.w;
  float s2 = v.x*v.x + v.y*v.y + v.z*v.z + v.w*v.w;
  #pragma unroll
  for (int d = 32; d; d >>= 1) { s += __shfl_down(s, d); s2 += __shfl_down(s2, d); }
  __shared__ float rs[4], rq[4];
  int lane = t & 63, w = t >> 6;
  if (lane == 0) { rs[w] = s; rq[w] = s2; }
  __syncthreads();
  float mean = (rs[0]+rs[1]+rs[2]+rs[3]) * (1.0f/En);
  float var  = (rq[0]+rq[1]+rq[2]+rq[3]) * (1.0f/En) - mean*mean;
  float rstd = rsqrtf(var + 1e-5f);
  float4 gg = ((const float4*)g)[t];
  float4 bv = ((const float4*)bb)[t];
  float o0 = (v.x-mean)*rstd*gg.x + bv.x;
  float o1 = (v.y-mean)*rstd*gg.y + bv.y;
  float o2 = (v.z-mean)*rstd*gg.z + bv.z;
  float o3 = (v.w-mean)*rstd*gg.w + bv.w;
  if (outf) { float4 ov = {o0,o1,o2,o3}; ((float4*)(outf + (size_t)n*En))[t] = ov; }
  if (outb) {
    uint2 o;
    o.x = (unsigned int)f2b(o0) | ((unsigned int)f2b(o1) << 16);
    o.y = (unsigned int)f2b(o2) | ((unsigned int)f2b(o3) << 16);
    ((uint2*)(outb + (size_t)n*En))[t] = o;
  }
}

// ======== 256x256 GEMM, 4 half-tile ring buffers + counted vmcnt (T1..T5) ========
// EPI 4: f32 out | EPI 5: bf16 out no-bias | EPI 0 + NOUT2: bf16 out (+bias), split N
// LDS 128 KiB: 4 half-buffers x (A[256][32] + B[256][32]) bf16, st_16x32 swizzle.
template<int EPI, bool AGATHER, int NOUT, int LSWZ>
__global__ __launch_bounds__(512) void k_gemm256(
    const unsigned short* __restrict__ Ab, const unsigned short* __restrict__ Bb,
    const int* __restrict__ gidx, const float* __restrict__ bias,
    float* __restrict__ Cf, unsigned short* __restrict__ cb0, unsigned short* __restrict__ cb1,
    int Ndim, int Kdim, int nRT, int nCT) {
  extern __shared__ unsigned short lds[];
  const int t = threadIdx.x, lane = t & 63, w = t >> 6;
  const int wr = w >> 2, wc = w & 3, l15 = lane & 15, l4 = lane >> 4;
  const int lr2 = lane >> 2;
  const int cg  = (lane & 3) ^ (((lane >> 5) & 1) << 1);   // source pre-swizzle (involution)

  // bijective chunked XCD map
  const int nwg = nRT * nCT;
  int lb = ((int)blockIdx.x % 8) * (nwg >> 3) + ((int)blockIdx.x >> 3);
  int rowT, colT;
  if (LSWZ == 0) { rowT = lb % nRT; colT = lb / nRT; }
  else           { colT = lb % nCT; rowT = lb / nCT; }
  const int row0 = rowT * 256, col0 = colT * 256;

  auto pa = [&](int h) -> unsigned short* { return lds + h * 16384; };
  auto pb = [&](int h) -> unsigned short* { return lds + h * 16384 + 8192; };

  const unsigned short *aSrc0, *aSrc1;
  if constexpr (AGATHER) {
    aSrc0 = Ab + (size_t)gidx[row0 + w * 32 + lr2] * Kdim + cg * 8;
    aSrc1 = Ab + (size_t)gidx[row0 + w * 32 + 16 + lr2] * Kdim + cg * 8;
  } else {
    aSrc0 = Ab + (size_t)(row0 + w * 32 + lr2) * Kdim + cg * 8;
    aSrc1 = aSrc0 + (size_t)16 * Kdim;
  }
  const unsigned short* bSrc0 = Bb + (size_t)(col0 + w * 32 + lr2) * Kdim + cg * 8;
  const unsigned short* bSrc1 = bSrc0 + (size_t)16 * Kdim;

  f32x4 acc[8][4];
  #pragma unroll
  for (int i = 0; i < 8; i++)
    #pragma unroll
    for (int j = 0; j < 4; j++) acc[i][j] = (f32x4){0.f, 0.f, 0.f, 0.f};

  const int NH = Kdim >> 5;                 // K half-tiles of 32
  #pragma unroll
  for (int h = 0; h < 3; ++h) {
    const int ko = h * 32;
    gload16(aSrc0 + ko, pa(h) + w*32*32);
    gload16(aSrc1 + ko, pa(h) + (w*32+16)*32);
    gload16(bSrc0 + ko, pb(h) + w*32*32);
    gload16(bSrc1 + ko, pb(h) + (w*32+16)*32);
  }
  asm volatile("s_waitcnt vmcnt(8)" ::: "memory");   // half 0 landed
  __builtin_amdgcn_s_barrier();
  MEMFENCE;

  for (int hs = 0; hs < NH; ++hs) {
    const int cur = hs & 3;
    const unsigned short* Ap = pa(cur);
    const unsigned short* Bp = pb(cur);
    const int h3 = (hs + 3) & 3, ko3 = (hs + 3) * 32;
    const bool pf = (hs + 3) < NH;
    bf16x8 bfr[4], af[4];

    // ---- phase 0: B frags + A rows 0..63 ----
    #pragma unroll
    for (int ni = 0; ni < 4; ni++) {
      int row = wc * 64 + ni * 16 + l15;
      int c8 = l4 ^ (((row >> 3) & 1) << 1);
      bfr[ni] = *(const bf16x8*)&Bp[row * 32 + c8 * 8];
    }
    #pragma unroll
    for (int m = 0; m < 4; m++) {
      int row = wr * 128 + m * 16 + l15;
      int c8 = l4 ^ (((row >> 3) & 1) << 1);
      af[m] = *(const bf16x8*)&Ap[row * 32 + c8 * 8];
    }
    if (pf) {
      gload16(aSrc0 + ko3, pa(h3) + w*32*32);
      gload16(aSrc1 + ko3, pa(h3) + (w*32+16)*32);
    }
    MEMFENCE; __builtin_amdgcn_s_barrier(); MEMFENCE;
    __builtin_amdgcn_s_setprio(1);
    #pragma unroll
    for (int m = 0; m < 4; m++)
      #pragma unroll
      for (int ni = 0; ni < 4; ni++)
        acc[m][ni] = __builtin_amdgcn_mfma_f32_16x16x32_bf16(af[m], bfr[ni], acc[m][ni], 0, 0, 0);
    __builtin_amdgcn_s_setprio(0);
    MEMFENCE; __builtin_amdgcn_s_barrier(); MEMFENCE;

    // ---- phase 1: A rows 64..127 ----
    #pragma unroll
    for (int m = 0; m < 4; m++) {
      int row = wr * 128 + (4 + m) * 16 + l15;
      int c8 = l4 ^ (((row >> 3) & 1) << 1);
      af[m] = *(const bf16x8*)&Ap[row * 32 + c8 * 8];
    }
    if (pf) {
      gload16(bSrc0 + ko3, pb(h3) + w*32*32);
      gload16(bSrc1 + ko3, pb(h3) + (w*32+16)*32);
    }
    MEMFENCE; __builtin_amdgcn_s_barrier(); MEMFENCE;
    __builtin_amdgcn_s_setprio(1);
    #pragma unroll
    for (int m = 0; m < 4; m++)
      #pragma unroll
      for (int ni = 0; ni < 4; ni++)
        acc[4 + m][ni] = __builtin_amdgcn_mfma_f32_16x16x32_bf16(af[m], bfr[ni], acc[4 + m][ni], 0, 0, 0);
    __builtin_amdgcn_s_setprio(0);

    if (hs + 1 < NH) {
      const int rem = NH - 2 - hs;          // prefetched halves beyond hs+1
      if (rem >= 2)      asm volatile("s_waitcnt vmcnt(8)" ::: "memory");
      else if (rem == 1) asm volatile("s_waitcnt vmcnt(4)" ::: "memory");
      else               asm volatile("s_waitcnt vmcnt(0)" ::: "memory");
      __builtin_amdgcn_s_barrier();
      MEMFENCE;
    }
  }

  #pragma unroll
  for (int m = 0; m < 8; m++) {
    #pragma unroll
    for (int ni = 0; ni < 4; ni++) {
      int col  = col0 + wc * 64 + ni * 16 + l15;
      int rowb = row0 + wr * 128 + m * 16 + l4 * 4;
      #pragma unroll
      for (int r = 0; r < 4; r++) {
        float v = acc[m][ni][r];
        if constexpr (EPI == 4) {
          Cf[(size_t)(rowb + r) * Ndim + col] = v;
        } else if constexpr (EPI == 5) {
          cb0[(size_t)(rowb + r) * Ndim + col] = f2b(v);
        } else {
          unsigned short* cb = (col >> 10) ? cb1 : cb0;
          cb[(size_t)(rowb + r) * 1024 + (col & 1023)] = f2b(v + bias[col]);
        }
      }
    }
  }
}

// ---------------- GEMM 128x128 (2-phase) for the small GEMMs ----------------
template<int EPI, bool AGATHER, bool SWAPG, int NOUT>
__global__ __launch_bounds__(256) void k_gemm(
    const unsigned short* __restrict__ Ab, const unsigned short* __restrict__ Bb,
    const int* __restrict__ gidx,
    const float* __restrict__ bias, const float* __restrict__ resid,
    float* __restrict__ Cf, unsigned short* __restrict__ cb0,
    unsigned short* __restrict__ cb1, unsigned short* __restrict__ cb2,
    int Ndim, int Kdim) {
  __shared__ unsigned short As[128][32];
  __shared__ unsigned short Bs[128][32];
  const int t = threadIdx.x, lane = t & 63, w = t >> 6;
  const int wr = w >> 1, wc = w & 1, l15 = lane & 15, l4 = lane >> 4;
  const int row0 = (SWAPG ? blockIdx.x : blockIdx.y) * 128;
  const int col0 = (SWAPG ? blockIdx.y : blockIdx.x) * 128;
  const int c8  = (lane & 3) * 8;
  const int r16 = lane >> 2;
  const int rA0 = w * 32 + r16, rA1 = rA0 + 16;

  size_t raA0, raA1, raB0, raB1;
  if constexpr (AGATHER) {
    raA0 = (size_t)gidx[row0 + rA0] * Kdim;
    raA1 = (size_t)gidx[row0 + rA1] * Kdim;
  } else {
    raA0 = (size_t)(row0 + rA0) * Kdim;
    raA1 = (size_t)(row0 + rA1) * Kdim;
  }
  raB0 = (size_t)(col0 + rA0) * Kdim;
  raB1 = (size_t)(col0 + rA1) * Kdim;

  f32x4 acc[4][4];
  #pragma unroll
  for (int i = 0; i < 4; i++)
    #pragma unroll
    for (int j = 0; j < 4; j++) acc[i][j] = (f32x4){0.f,0.f,0.f,0.f};

  for (int kt0 = 0; kt0 < Kdim; kt0 += 32) {
    __syncthreads();
    gload16(Ab + raA0 + kt0 + c8, &As[w * 32][0]);
    gload16(Ab + raA1 + kt0 + c8, &As[w * 32 + 16][0]);
    gload16(Bb + raB0 + kt0 + c8, &Bs[w * 32][0]);
    gload16(Bb + raB1 + kt0 + c8, &Bs[w * 32 + 16][0]);
    __syncthreads();
    bf16x8 af[4], bfr[4];
    #pragma unroll
    for (int mi = 0; mi < 4; mi++) af[mi]  = *(const bf16x8*)&As[wr*64 + mi*16 + l15][l4*8];
    #pragma unroll
    for (int ni = 0; ni < 4; ni++) bfr[ni] = *(const bf16x8*)&Bs[wc*64 + ni*16 + l15][l4*8];
    #pragma unroll
    for (int mi = 0; mi < 4; mi++)
      #pragma unroll
      for (int ni = 0; ni < 4; ni++)
        acc[mi][ni] = __builtin_amdgcn_mfma_f32_16x16x32_bf16(af[mi], bfr[ni], acc[mi][ni], 0, 0, 0);
  }

  unsigned short* cbase = cb0;
  int colsub = 0;
  if constexpr (NOUT > 1) {
    int which = col0 >> 10;
    cbase = (which == 0) ? cb0 : (which == 1) ? cb1 : cb2;
    colsub = col0 & 1023;
  }

  #pragma unroll
  for (int mi = 0; mi < 4; mi++) {
    #pragma unroll
    for (int ni = 0; ni < 4; ni++) {
      int col  = col0 + wc*64 + ni*16 + l15;
      int rowb = row0 + wr*64 + mi*16 + l4*4;
      #pragma unroll
      for (int r = 0; r < 4; r++) {
        float v = acc[mi][ni][r];
        size_t off = (size_t)(rowb + r) * Ndim + col;
        if constexpr (EPI == 0) {
          if constexpr (NOUT > 1) {
            int c2 = colsub + wc*64 + ni*16 + l15;
            cbase[(size_t)(rowb + r) * 1024 + c2] = f2b(v + bias[col]);
          } else {
            cb0[off] = f2b(v + bias[col]);
          }
        } else if constexpr (EPI == 1) {
          Cf[off] = v + bias[col] + resid[off];
        } else if constexpr (EPI == 2) {
          float u = v + bias[col];
          u = 0.5f * u * (1.0f + erff(u * 0.70710678118654752f));
          cb0[off] = f2b(u);
        } else {
          Cf[off] = v;
        }
      }
    }
  }
}

// ---------------- fused attention (flash-style) with optional KV-split ----------------
template<int SPLIT>
__global__ __launch_bounds__(256) void k_attn(
    const unsigned short* __restrict__ Qp, const unsigned short* __restrict__ Kp,
    const unsigned short* __restrict__ Vp, unsigned short* __restrict__ Op,
    float* __restrict__ PO, float* __restrict__ PM, float* __restrict__ PL, int Lk) {
  __shared__ unsigned short Ks[64][72];
  __shared__ unsigned short Vt[64][72];   // V transposed (k-chunk XOR-swizzled by d>>3)
  __shared__ float Ps[4][16][68];         // per-wave P transpose buffer
  const int b = blockIdx.z / SPLIT, sp = blockIdx.z % SPLIT;
  const int h = blockIdx.y, q0 = blockIdx.x * 64;
  const int t = threadIdx.x, lane = t & 63, w = t >> 6;
  const int l15 = lane & 15, l4 = lane >> 4;

  const int qrow = q0 + w * 16 + l15;
  const unsigned short* qptr = Qp + (size_t)(b * Sn + qrow) * En + h * 64 + l4 * 8;
  bf16x8 qf0 = *(const bf16x8*)qptr;
  bf16x8 qf1 = *(const bf16x8*)(qptr + 32);

  f32x4 oacc[4];
  #pragma unroll
  for (int i = 0; i < 4; i++) oacc[i] = (f32x4){0.f,0.f,0.f,0.f};
  float m_[4] = {-INFINITY, -INFINITY, -INFINITY, -INFINITY};
  float l_[4] = {0.f, 0.f, 0.f, 0.f};

  const int nkt = Lk / (64 * SPLIT);
  for (int kt = sp * nkt; kt < (sp + 1) * nkt; ++kt) {
    __syncthreads();
    #pragma unroll
    for (int i = 0; i < 2; i++) {
      int ld = t + i * 256;
      int kr = ld >> 3, d8 = (ld & 7) * 8;
      size_t base = (size_t)(b * Lk + kt * 64 + kr) * En + h * 64 + d8;
      *(uint4*)&Ks[kr][d8] = *(const uint4*)(Kp + base);
      bf16x8 vv = *(const bf16x8*)(Vp + base);
      int colswz = kr ^ ((t & 7) << 3);
      #pragma unroll
      for (int j = 0; j < 8; j++) Vt[d8 + j][colswz] = ((unsigned short*)&vv)[j];
    }
    __syncthreads();

    f32x4 s[4];
    #pragma unroll
    for (int ni = 0; ni < 4; ni++) {
      s[ni] = (f32x4){0.f,0.f,0.f,0.f};
      bf16x8 kb0 = *(const bf16x8*)&Ks[ni*16 + l15][l4*8];
      bf16x8 kb1 = *(const bf16x8*)&Ks[ni*16 + l15][l4*8 + 32];
      s[ni] = __builtin_amdgcn_mfma_f32_16x16x32_bf16(qf0, kb0, s[ni], 0, 0, 0);
      s[ni] = __builtin_amdgcn_mfma_f32_16x16x32_bf16(qf1, kb1, s[ni], 0, 0, 0);
    }

    #pragma unroll
    for (int r = 0; r < 4; r++) {
      #pragma unroll
      for (int ni = 0; ni < 4; ni++) s[ni][r] *= 0.125f;
      float mx = fmaxf(fmaxf(s[0][r], s[1][r]), fmaxf(s[2][r], s[3][r]));
      #pragma unroll
      for (int d2 = 1; d2 < 16; d2 <<= 1) mx = fmaxf(mx, __shfl_xor(mx, d2));
      float mn = fmaxf(m_[r], mx);
      float alpha = expf(m_[r] - mn);
      float rsum = 0.f;
      #pragma unroll
      for (int ni = 0; ni < 4; ni++) { float p = expf(s[ni][r] - mn); s[ni][r] = p; rsum += p; }
      #pragma unroll
      for (int d2 = 1; d2 < 16; d2 <<= 1) rsum += __shfl_xor(rsum, d2);
      l_[r] = l_[r] * alpha + rsum;
      m_[r] = mn;
      #pragma unroll
      for (int nd = 0; nd < 4; nd++) oacc[nd][r] *= alpha;
    }

    #pragma unroll
    for (int ni = 0; ni < 4; ni++)
      #pragma unroll
      for (int r = 0; r < 4; r++)
        Ps[w][l4*4 + r][ni*16 + l15] = s[ni][r];
    asm volatile("s_waitcnt lgkmcnt(0)" ::: "memory");

    #pragma unroll
    for (int half = 0; half < 2; half++) {
      float4 pv0 = *(const float4*)&Ps[w][l15][half*32 + l4*8];
      float4 pv1 = *(const float4*)&Ps[w][l15][half*32 + l4*8 + 4];
      bf16x8 pa;
      pa[0]=(short)f2b(pv0.x); pa[1]=(short)f2b(pv0.y); pa[2]=(short)f2b(pv0.z); pa[3]=(short)f2b(pv0.w);
      pa[4]=(short)f2b(pv1.x); pa[5]=(short)f2b(pv1.y); pa[6]=(short)f2b(pv1.z); pa[7]=(short)f2b(pv1.w);
      #pragma unroll
      for (int nd = 0; nd < 4; nd++) {
        int dd = nd*16 + l15;
        bf16x8 vb = *(const bf16x8*)&Vt[dd][(half*32 + l4*8) ^ (((dd >> 3) & 7) << 3)];
        oacc[nd] = __builtin_amdgcn_mfma_f32_16x16x32_bf16(pa, vb, oacc[nd], 0, 0, 0);
      }
    }
  }

  if constexpr (SPLIT == 1) {
    #pragma unroll
    for (int nd = 0; nd < 4; nd++)
      #pragma unroll
      for (int r = 0; r < 4; r++) {
        int q = q0 + w*16 + l4*4 + r;
        Op[(size_t)(b * Sn + q) * En + h * 64 + nd*16 + l15] = f2b(oacc[nd][r] / l_[r]);
      }
  } else {
    const int slot = ((b * Hn + h) * 4 + blockIdx.x) * SPLIT + sp;
    #pragma unroll
    for (int nd = 0; nd < 4; nd++)
      #pragma unroll
      for (int r = 0; r < 4; r++)
        PO[slot * 4096 + (w*16 + l4*4 + r) * 64 + nd*16 + l15] = oacc[nd][r];
    if (l15 == 0) {
      #pragma unroll
      for (int r = 0; r < 4; r++) {
        PM[slot * 64 + w*16 + l4*4 + r] = m_[r];
        PL[slot * 64 + w*16 + l4*4 + r] = l_[r];
      }
    }
  }
}

// ---------------- combine split-K attention partials (SPLIT=4) ----------------
__global__ __launch_bounds__(256) void k_attn_comb(
    const float* __restrict__ PO, const float* __restrict__ PM,
    const float* __restrict__ PL, unsigned short* __restrict__ Op) {
  const int W = blockIdx.x * 4 + (threadIdx.x >> 6);
  const int lane = threadIdx.x & 63;
  const int bh = W >> 8, q = W & 255;
  const int qb = q >> 6, qq = q & 63;
  const int slotBase = (bh * 4 + qb) * 4;
  float ms[4];
  float M = -INFINITY;
  #pragma unroll
  for (int s = 0; s < 4; s++) { ms[s] = PM[(slotBase + s) * 64 + qq]; M = fmaxf(M, ms[s]); }
  float L = 0.f, acc = 0.f;
  #pragma unroll
  for (int s = 0; s < 4; s++) {
    float wgt = expf(ms[s] - M);
    L += PL[(slotBase + s) * 64 + qq] * wgt;
    acc += wgt * PO[(size_t)(slotBase + s) * 4096 + qq * 64 + lane];
  }
  const int b = bh >> 4, h = bh & 15;
  Op[(size_t)(b * Sn + q) * En + h * 64 + lane] = f2b(acc / L);
}

// ------------- helpers for radix top-k -------------
DEVFN unsigned blk_exscan(unsigned part, volatile unsigned* wsum, int lane, int wid) {
  unsigned v = part;
  #pragma unroll
  for (int d = 1; d < 64; d <<= 1) { unsigned o = __shfl_up(v, d); if (lane >= d) v += o; }
  if (lane == 63) wsum[wid] = v;
  __syncthreads();
  unsigned woff = 0;
  for (int i = 0; i < wid; i++) woff += wsum[i];
  unsigned r = woff + v - part;
  __syncthreads();
  return r;
}

DEVFN void find_thr(const unsigned* hist, int NB, unsigned need,
                    int t, int lane, int wid, volatile unsigned* wsum,
                    volatile int* s_thr, volatile unsigned* s_above) {
  int per = NB >> 9;
  int lo = NB - per * (t + 1);
  unsigned part = 0;
  for (int j = 0; j < per; j++) part += hist[lo + j];
  unsigned ex = blk_exscan(part, wsum, lane, wid);
  if (ex < need && ex + part >= need) {
    unsigned c = ex;
    for (int j = per - 1; j >= 0; j--) {
      unsigned h = hist[lo + j];
      if (c + h >= need) { *s_thr = lo + j; *s_above = c; break; }
      c += h;
    }
  }
  __syncthreads();
}

// ------- exact top-32 per row on bf16 keys: 11-bit + 5-bit radix + tie pass -------
__global__ __launch_bounds__(512) void k_topk16(
    const unsigned short* __restrict__ simsb, int* __restrict__ oidx) {
  const int n = blockIdx.x, t = threadIdx.x;
  const int lane = t & 63, wid = t >> 6;
  const u16x8* row8 = (const u16x8*)(simsb + (size_t)n * Mn);
  __shared__ unsigned hw[8][2048];     // per-wave hists (contention relief)
  __shared__ unsigned hist[2048];
  __shared__ unsigned wsum[8];
  __shared__ int s_thr;
  __shared__ unsigned s_above;
  __shared__ unsigned h2[32];
  __shared__ int slist[32];
  __shared__ unsigned sL, sneedEq, stie;

  for (int i = t; i < 16384; i += 512) ((unsigned*)hw)[i] = 0;
  if (t < 32) h2[t] = 0;
  __syncthreads();
  #pragma unroll 4
  for (int p = 0; p < 16; p++) {
    u16x8 v = row8[p * 512 + t];
    #pragma unroll
    for (int j = 0; j < 8; j++) atomicAdd(&hw[wid][okey16(v[j]) >> 5], 1u);
  }
  __syncthreads();
  for (int i = t; i < 2048; i += 512) {
    unsigned s = 0;
    #pragma unroll
    for (int q = 0; q < 8; q++) s += hw[q][i];
    hist[i] = s;
  }
  __syncthreads();
  find_thr(hist, 2048, 32, t, lane, wid, wsum, &s_thr, &s_above);
  const unsigned T1 = (unsigned)s_thr;
  const unsigned need2 = 32 - s_above;
  const unsigned cnt1 = hist[T1];

  unsigned L, istar = 0xFFFFFFFFu;
  if (cnt1 == need2) {
    L = T1 << 5;                                   // whole bin accepted
  } else {
    // P2: low-5-bit histogram within bin T1 (L3-resident re-read)
    for (int p = 0; p < 16; p++) {
      u16x8 v = row8[p * 512 + t];
      #pragma unroll
      for (int j = 0; j < 8; j++) {
        unsigned k = okey16(v[j]);
        if ((k >> 5) == T1) atomicAdd(&h2[k & 31], 1u);
      }
    }
    __syncthreads();
    if (t == 0) {
      unsigned cum = 0; int T3 = 0; unsigned above = 0;
      for (int j = 31; j >= 0; j--) {
        if (cum + h2[j] >= need2) { T3 = j; above = cum; break; }
        cum += h2[j];
      }
      sL = (T1 << 5) | (unsigned)T3;
      sneedEq = need2 - above;
      stie = (h2[T3] != need2 - above);            // excess exact ties?
    }
    __syncthreads();
    L = sL;
    if (stie) {
      // ordered compaction over contiguous per-thread segments -> smallest needEq indices
      const unsigned short* rowp = simsb + (size_t)n * Mn;
      unsigned cntLoc = 0;
      for (int j = 0; j < 128; j++)
        if (okey16(rowp[t * 128 + j]) == L) cntLoc++;
      unsigned pre = blk_exscan(cntLoc, wsum, lane, wid);
      unsigned c = 0;
      for (int j = 0; j < 128; j++)
        if (okey16(rowp[t * 128 + j]) == L) { if (pre + c < 32) slist[pre + c] = t * 128 + j; c++; }
      __syncthreads();
      istar = (unsigned)slist[sneedEq - 1];
    }
  }
  __syncthreads();

  // emit (set-exact; order arbitrary -- softmax is permutation-invariant)
  unsigned cnt = 0;
  for (int p = 0; p < 16; p++) {
    u16x8 v = row8[p * 512 + t];
    unsigned i0 = (unsigned)(p * 512 + t) * 8;
    #pragma unroll
    for (int j = 0; j < 8; j++) {
      unsigned k = okey16(v[j]);
      cnt += (k > L || (k == L && i0 + j <= istar));
    }
  }
  unsigned pos = blk_exscan(cnt, wsum, lane, wid);
  for (int p = 0; p < 16; p++) {
    u16x8 v = row8[p * 512 + t];
    unsigned i0 = (unsigned)(p * 512 + t) * 8;
    #pragma unroll
    for (int j = 0; j < 8; j++) {
      unsigned k = okey16(v[j]);
      if (k > L || (k == L && i0 + j <= istar)) oidx[n * Kt + pos++] = (int)(i0 + j);
    }
  }
}

// =============================== host ===============================
extern "C" void kernel_launch(void* const* d_in, const int* in_sizes, int n_in,
                              void* d_out, int out_size, void* d_ws, size_t ws_size,
                              hipStream_t stream) {
  (void)in_sizes; (void)n_in; (void)out_size;
  const float* x      = (const float*)d_in[0];
  const float* mem_k  = (const float*)d_in[1];
  const float* mem_v  = (const float*)d_in[2];
  const float* sa_w[4] = {(const float*)d_in[3], (const float*)d_in[4], (const float*)d_in[5], (const float*)d_in[6]};
  const float* sa_b[4] = {(const float*)d_in[7], (const float*)d_in[8], (const float*)d_in[9], (const float*)d_in[10]};
  const float* ma_w[4] = {(const float*)d_in[11], (const float*)d_in[12], (const float*)d_in[13], (const float*)d_in[14]};
  const float* ma_b[4] = {(const float*)d_in[15], (const float*)d_in[16], (const float*)d_in[17], (const float*)d_in[18]};
  const float* ln_g[3] = {(const float*)d_in[19], (const float*)d_in[21], (const float*)d_in[23]};
  const float* ln_b[3] = {(const float*)d_in[20], (const float*)d_in[22], (const float*)d_in[24]};
  const float* fc1_w = (const float*)d_in[25];
  const float* fc1_b = (const float*)d_in[26];
  const float* fc2_w = (const float*)d_in[27];
  const float* fc2_b = (const float*)d_in[28];
  float* out = (float*)d_out;

  char* ws = (char*)d_ws;
  size_t off = 0;
  auto alloc = [&](size_t bytes) -> char* {
    char* p = ws + off;
    off = (off + bytes + 255) & ~(size_t)255;
    return p;
  };

  unsigned short* wt[8];
  for (int i = 0; i < 8; i++) wt[i] = (unsigned short*)alloc((size_t)En * En * 2);  // contiguous
  unsigned short* fc1t  = (unsigned short*)alloc((size_t)FFn * En * 2);
  unsigned short* fc2t  = (unsigned short*)alloc((size_t)En * FFn * 2);
  unsigned short* xb    = (unsigned short*)alloc((size_t)NT * En * 2);
  unsigned short* Qb    = (unsigned short*)alloc((size_t)NT * En * 2);
  unsigned short* Kb    = (unsigned short*)alloc((size_t)NT * En * 2);
  unsigned short* Vb    = (unsigned short*)alloc((size_t)NT * En * 2);
  unsigned short* at1b  = (unsigned short*)alloc((size_t)NT * En * 2);
  float*          t1    = (float*)alloc((size_t)NT * En * 4);
  float*          x1f   = (float*)alloc((size_t)NT * En * 4);
  unsigned short* x1b   = (unsigned short*)alloc((size_t)NT * En * 2);
  char*           simsRaw = alloc((size_t)NT * Mn * 4);                // 256 MiB region
  int*            idx   = (int*)alloc((size_t)NT * Kt * 4);
  unsigned short* K2b   = (unsigned short*)alloc((size_t)NT * Kt * En * 2);  // 64 MiB
  unsigned short* V2b   = (unsigned short*)alloc((size_t)NT * Kt * En * 2);  // contiguous after K2b
  unsigned short* Q2b   = (unsigned short*)alloc((size_t)NT * En * 2);
  unsigned short* at2b  = (unsigned short*)alloc((size_t)NT * En * 2);
  float*          t2    = (float*)alloc((size_t)NT * En * 4);
  float*          x2f   = (float*)alloc((size_t)NT * En * 4);
  unsigned short* x2b   = (unsigned short*)alloc((size_t)NT * En * 2);
  unsigned short* hb    = (unsigned short*)alloc((size_t)NT * FFn * 2);
  float*          t3    = (float*)alloc((size_t)NT * En * 4);
  float*          bcat_sa = (float*)alloc(3072 * 4);
  float*          bcat_ma = (float*)alloc(2048 * 4);

  if (off > ws_size) return;   // insufficient workspace: leave output poisoned (fail loudly)

  // Overlays (dead-region reuse):
  unsigned short* simsb = (unsigned short*)simsRaw;   // bf16 sims: 128 MiB of the region
  unsigned short* mkb = (unsigned short*)K2b;         // until sims GEMM done
  unsigned short* mvb = (unsigned short*)simsRaw;     // after topk
  float* PO = (float*)(simsRaw + (size_t)128 * 1024 * 1024);
  float* PM = PO + (size_t)1024 * 4096;
  float* PL = PM + (size_t)1024 * 64;

  // allow 128 KiB dynamic LDS for the 256^2 kernels (best effort)
  (void)hipFuncSetAttribute((const void*)&k_gemm256<5,false,1,0>,
                            hipFuncAttributeMaxDynamicSharedMemorySize, 131072);
  (void)hipFuncSetAttribute((const void*)&k_gemm256<0,true,2,1>,
                            hipFuncAttributeMaxDynamicSharedMemorySize, 131072);

  // ---- prep: weight transposes to bf16 [N][K], bias concats ----
  for (int i = 0; i < 4; i++)
    k_transpose_bf16<<<dim3(16, 16), 256, 0, stream>>>(sa_w[i], wt[i], En, En);
  for (int i = 0; i < 4; i++)
    k_transpose_bf16<<<dim3(16, 16), 256, 0, stream>>>(ma_w[i], wt[4 + i], En, En);
  k_transpose_bf16<<<dim3(64, 16), 256, 0, stream>>>(fc1_w, fc1t, En, FFn);
  k_transpose_bf16<<<dim3(16, 64), 256, 0, stream>>>(fc2_w, fc2t, FFn, En);
  k_concat3<<<dim3(12), 256, 0, stream>>>(sa_b[0], sa_b[1], sa_b[2], bcat_sa);
  k_concat3<<<dim3(8),  256, 0, stream>>>(ma_b[1], ma_b[2], ma_b[2], bcat_ma);

  k_cvt_bf16<<<dim3(NT * En / 4 / 256), 256, 0, stream>>>(x, xb, NT * En / 4);
  k_normcvt<<<dim3(Mn), 256, 0, stream>>>(mem_k, mkb);

  const dim3 g1(En / 128, NT / 128);   // (8,8)

  // ---- self-attention (QKV fused: N=3072 over contiguous wt[0..2]) ----
  k_gemm<0,false,false,3><<<dim3(24, 8), 256, 0, stream>>>(xb, wt[0], nullptr, bcat_sa, nullptr, nullptr, Qb, Kb, Vb, 3072, En);
  k_attn<1><<<dim3(Sn / 64, Hn, Bn), 256, 0, stream>>>(Qb, Kb, Vb, at1b, nullptr, nullptr, nullptr, Sn);
  k_gemm<1,false,false,1><<<g1, 256, 0, stream>>>(at1b, wt[3], nullptr, sa_b[3], x, t1, nullptr, nullptr, nullptr, En, En);
  k_layernorm<<<NT, 256, 0, stream>>>(t1, ln_g[0], ln_b[0], x1f, x1b);

  // ---- retrieval: sims in bf16 (L3-resident) + 16-bit radix top-k ----
  k_gemm256<5,false,1,0><<<dim3(1024), 512, 131072, stream>>>(
      x1b, mkb, nullptr, nullptr, nullptr, simsb, nullptr, Mn, En, NT / 256, Mn / 256);
  k_topk16<<<NT, 512, 0, stream>>>(simsb, idx);

  // ---- memory cross-attention (K2/V2 fused 256^2 over contiguous wt[5..6]) ----
  k_cvt_bf16<<<dim3(Mn * En / 4 / 256), 256, 0, stream>>>(mem_v, mvb, Mn * En / 4);
  k_gemm256<0,true,2,1><<<dim3(1024), 512, 131072, stream>>>(
      mvb, wt[5], idx, bcat_ma, nullptr, K2b, V2b, 2048, En, NT * Kt / 256, 2048 / 256);
  k_gemm<0,false,false,1><<<g1, 256, 0, stream>>>(x1b, wt[4], nullptr, ma_b[0], nullptr, nullptr, Q2b, nullptr, nullptr, En, En);
  k_attn<4><<<dim3(Sn / 64, Hn, Bn * 4), 256, 0, stream>>>(Q2b, K2b, V2b, nullptr, PO, PM, PL, Sn * Kt);
  k_attn_comb<<<dim3(Bn * Hn * Sn / 4), 256, 0, stream>>>(PO, PM, PL, at2b);
  k_gemm<1,false,false,1><<<g1, 256, 0, stream>>>(at2b, wt[7], nullptr, ma_b[3], x1f, t2, nullptr, nullptr, nullptr, En, En);
  k_layernorm<<<NT, 256, 0, stream>>>(t2, ln_g[1], ln_b[1], x2f, x2b);

  // ---- FFN ----
  k_gemm<2,false,false,1><<<dim3(FFn / 128, NT / 128), 256, 0, stream>>>(x2b, fc1t, nullptr, fc1_b, nullptr, nullptr, hb, nullptr, nullptr, FFn, En);
  k_gemm<1,false,false,1><<<g1, 256, 0, stream>>>(hb, fc2t, nullptr, fc2_b, x2f, t3, nullptr, nullptr, nullptr, En, FFn);
  k_layernorm<<<NT, 256, 0, stream>>>(t3, ln_g[2], ln_b[2], out, nullptr);
}